// Round 9
// baseline (568.237 us; speedup 1.0000x reference)
//
#include <hip/hip_runtime.h>
#include <hip/hip_bf16.h>

typedef float f32x4 __attribute__((ext_vector_type(4)));
typedef short bf16x8 __attribute__((ext_vector_type(8)));
typedef unsigned short u16;

constexpr int T_TOK = 8192;
constexpr int KDIM  = 4096;
constexpr int NDIM  = 4096;
constexpr int NE    = 8;

constexpr long long TA = (long long)T_TOK * KDIM;
constexpr long long TB = (long long)NE * NDIM * KDIM;

__device__ __forceinline__ u16 f2bf(float f) {
  unsigned u = __builtin_bit_cast(unsigned, f);
  u += 0x7FFFu + ((u >> 16) & 1u);
  return (u16)(u >> 16);
}

// ---------------- pass 1: fp32 -> bf16 streaming convert ---------------------
__global__ __launch_bounds__(256)
void cvt_bf16(const float* __restrict__ A, const float* __restrict__ B,
              u16* __restrict__ oA, u16* __restrict__ oB) {
  const long long nv = (TA + TB) >> 3;
  const long long stride = (long long)gridDim.x * blockDim.x;
  for (long long i = (long long)blockIdx.x * blockDim.x + threadIdx.x; i < nv; i += stride) {
    const long long e = i << 3;
    const float* s;
    u16* d;
    if (e < TA) { s = A + e;        d = oA + e; }
    else        { s = B + (e - TA); d = oB + (e - TA); }
    f32x4 v0 = ((const f32x4*)s)[0];
    f32x4 v1 = ((const f32x4*)s)[1];
    bf16x8 p;
    #pragma unroll
    for (int j = 0; j < 4; ++j) p[j]     = (short)f2bf(v0[j]);
    #pragma unroll
    for (int j = 0; j < 4; ++j) p[4 + j] = (short)f2bf(v1[j]);
    *(bf16x8*)d = p;
  }
}

// ---------------- pass 2: 128x256, BK=32, 2 blocks/CU grouped GEMM -----------
__device__ __forceinline__ void gload16(const u16* g, const u16* l) {
  __builtin_amdgcn_global_load_lds(
      (const __attribute__((address_space(1))) void*)g,
      (__attribute__((address_space(3))) void*)l, 16, 0, 0);
}

constexpr int BM3 = 128, BN3 = 256, BK3 = 32;
constexpr int NKT3 = KDIM / BK3;          // 128 k-tiles
constexpr int NTN3 = NDIM / BN3;          // 16 n-tiles
constexpr int MT3  = T_TOK / BM3 + NE;    // 72 worst-case m-tiles
constexpr int NWG3 = MT3 * NTN3;          // 1152 (%8==0 -> simple XCD swizzle)
constexpr int ASZA = BM3 * BK3;           // 4096 elems (8 KB) per A buffer
constexpr int ASZB = BN3 * BK3;           // 8192 elems (16 KB) per B buffer
constexpr int LDS_BYTES = 2 * (ASZA + ASZB) * (int)sizeof(u16);   // 48 KB

// 512 threads = 8 waves; min 4 waves/EU => 2 blocks/CU. VGPR cap 128:
// acc 64 + aF/bF 32 + addressing ~15 => fits without spill.
__global__ __launch_bounds__(512, 4)
void gg8(const u16* __restrict__ Abf, const u16* __restrict__ Bbf,
         float* __restrict__ C, const int* __restrict__ segp,
         const int* __restrict__ widx)
{
  extern __shared__ u16 sm[];
  u16* sA = sm;                 // [2][4096]  (buf, 128 rows x 32 cols)
  u16* sB = sm + 2 * ASZA;      // [2][8192]  (buf, 256 rows x 32 cols)

  int bid = (int)blockIdx.x;
  bid = (bid & 7) * (NWG3 / 8) + (bid >> 3);   // XCD-aware bijective swizzle
  const int nt = bid % NTN3;
  const int mt = bid / NTN3;

  int e = -1, segs = 0, sege = 0, mloc = 0;
  {
    int acc0 = 0, sp = segp[0];
    #pragma unroll
    for (int i = 0; i < NE; ++i) {
      int sn = segp[i + 1];
      int nti = (sn - sp + BM3 - 1) / BM3;
      if (e < 0 && mt < acc0 + nti) { e = i; mloc = mt - acc0; segs = sp; sege = sn; }
      acc0 += nti; sp = sn;
    }
  }
  if (e < 0) return;

  const int row_base = segs + mloc * BM3;
  const int col_base = nt * BN3;
  const u16* __restrict__ W = Bbf + (long long)widx[e] * ((long long)NDIM * KDIM);

  const int tid = threadIdx.x, lane = tid & 63, wid = tid >> 6;
  const int wr = wid >> 2, wc = wid & 3;   // wave tile: rows wr*64+, cols wc*64+

  // ---- staging: linear LDS dest (uniform base + lane*16B), inverse-swizzled
  // global source. LDS tile rows are 64B (4 x 16B granules). LDS (row, g')
  // holds global granule g = g' ^ ((row>>1)&3)  [involution].
  // Wave-instr: lane l -> row R0+(l>>2), granule l&3; R0 % 16 == 0 =>
  // source granule = (l&3) ^ ((l>>3)&3).
  const int sgc = ((lane & 3) ^ ((lane >> 3) & 3)) * 8;  // src col elems
  int oA, oB0, oB1;
  {
    const int ra = row_base + wid * 16 + (lane >> 2);          // A rows: wave w -> w*16
    oA  = min(ra, T_TOK - 1) * KDIM + sgc;
    oB0 = (col_base + wid * 32 +      (lane >> 2)) * KDIM + sgc;  // B rows: w*32, +16
    oB1 = (col_base + wid * 32 + 16 + (lane >> 2)) * KDIM + sgc;
  }

  // ---- fragment reads (swizzled): frag row = base + (lane&15), base%16==0
  // => g' = (lane>>4) ^ ((lane>>1)&3)
  const int gp  = ((lane >> 4) ^ ((lane >> 1) & 3)) * 8;
  const int rA0 = (wr * 64 + (lane & 15)) * BK3 + gp;
  const int rB0 = (wc * 64 + (lane & 15)) * BK3 + gp;

  f32x4 acc[4][4];
  #pragma unroll
  for (int m = 0; m < 4; ++m)
    #pragma unroll
    for (int n = 0; n < 4; ++n)
      acc[m][n] = (f32x4){0.f, 0.f, 0.f, 0.f};

  auto STAGE = [&](int bbuf, int t) __attribute__((always_inline)) {
    gload16(Abf + oA  + t * BK3, sA + bbuf * ASZA + wid * 512);
    gload16(W   + oB0 + t * BK3, sB + bbuf * ASZB + wid * 1024);
    gload16(W   + oB1 + t * BK3, sB + bbuf * ASZB + wid * 1024 + 512);
  };

  // prologue: tile0 -> buf0, tile1 -> buf1 (6 loads/wave); vmcnt(3) -> tile0 in
  STAGE(0, 0); STAGE(1, 1);
  asm volatile("s_waitcnt vmcnt(3)" ::: "memory");
  __builtin_amdgcn_s_barrier();

  // Per tile: {8 ds_reads; lgkmcnt(0); BAR; STAGE(bb,t+2); 16 MFMA; vmcnt(3); BAR}
  // Ledger: at tile start outstanding = tile t+1 (3/wave); STAGE adds 3 ->
  // vmcnt(3) retires t+1 exactly. Tail (t+2>=NKT3): no stage -> vmcnt(0).
  // Races: lgkmcnt(0)+BAR before STAGE overwrites bb; tile t landed via
  // previous iteration's vmcnt.
  for (int t = 0; t < NKT3; ++t) {
    const int bb = t & 1;

    bf16x8 aF[4], bF[4];
    #pragma unroll
    for (int m = 0; m < 4; ++m)
      aF[m] = *(const bf16x8*)(sA + bb * ASZA + rA0 + m * 512);
    #pragma unroll
    for (int n = 0; n < 4; ++n)
      bF[n] = *(const bf16x8*)(sB + bb * ASZB + rB0 + n * 512);

    asm volatile("s_waitcnt lgkmcnt(0)" ::: "memory");
    __builtin_amdgcn_s_barrier();

    if (t + 2 < NKT3) STAGE(bb, t + 2);     // issue early; lands under MFMA

    __builtin_amdgcn_s_setprio(1);
    #pragma unroll
    for (int m = 0; m < 4; ++m)
      #pragma unroll
      for (int n = 0; n < 4; ++n)
        acc[m][n] = __builtin_amdgcn_mfma_f32_16x16x32_bf16(aF[m], bF[n], acc[m][n], 0, 0, 0);
    __builtin_amdgcn_s_setprio(0);

    if (t + 2 < NKT3) {
      asm volatile("s_waitcnt vmcnt(3)" ::: "memory");   // tile t+1 landed
    } else {
      asm volatile("s_waitcnt vmcnt(0)" ::: "memory");   // tail drain
    }
    __builtin_amdgcn_s_barrier();
  }

  // epilogue: frag (m,n) = rows wr*64+m*16+, cols wc*64+n*16+;
  // C/D layout: col = lane&15, row = (lane>>4)*4 + j
  #pragma unroll
  for (int m = 0; m < 4; ++m) {
    const int r0 = row_base + wr * 64 + m * 16 + ((lane >> 4) << 2);
    #pragma unroll
    for (int j = 0; j < 4; ++j) {
      const int r = r0 + j;
      if (r < sege) {
        float* cp = C + (long long)r * NDIM + col_base + wc * 64 + (lane & 15);
        #pragma unroll
        for (int n = 0; n < 4; ++n)
          cp[n * 16] = acc[m][n][j];
      }
    }
  }
}

// ---------------- fallback (round-1 fused convert+GEMM) ----------------------
constexpr int BM = 128, BN = 128, BK = 32;
constexpr int LDKF = BK + 8;
constexpr int NTN = NDIM / BN;
constexpr int MT_MAX = T_TOK / BM + NE;
constexpr int NKT = KDIM / BK;
constexpr int NWG = MT_MAX * NTN;

__global__ __launch_bounds__(256, 2)
void grouped_gemm_fused(const float* __restrict__ A, const float* __restrict__ B,
                        float* __restrict__ C, const int* __restrict__ segp,
                        const int* __restrict__ widx)
{
  __shared__ u16 lA[2][BM][LDKF];
  __shared__ u16 lB[2][BN][LDKF];

  const int nt = blockIdx.x % NTN;
  const int mt = blockIdx.x / NTN;

  int e = -1, segs = 0, sege = 0, mloc = 0;
  {
    int acc0 = 0, sp = segp[0];
    #pragma unroll
    for (int i = 0; i < NE; ++i) {
      int sn = segp[i + 1];
      int nti = (sn - sp + BM - 1) / BM;
      if (e < 0 && mt < acc0 + nti) { e = i; mloc = mt - acc0; segs = sp; sege = sn; }
      acc0 += nti; sp = sn;
    }
  }
  if (e < 0) return;

  const int row_base = segs + mloc * BM;
  const int col_base = nt * BN;
  const float* __restrict__ W = B + (long long)widx[e] * NDIM * KDIM;

  const int tid  = threadIdx.x;
  const int lane = tid & 63;
  const int wid  = tid >> 6;
  const int wr   = wid >> 1;
  const int wc   = wid & 1;

  const int srow = tid >> 1;
  const int scol = (tid & 1) << 4;
  const int arow = min(row_base + srow, T_TOK - 1);
  const float* __restrict__ aptr = A + (long long)arow * KDIM + scol;
  const float* __restrict__ bptr = W + (long long)(col_base + srow) * KDIM + scol;

  f32x4 sa[4], sb[4];
  f32x4 acc[4][4];
  #pragma unroll
  for (int m = 0; m < 4; ++m)
    #pragma unroll
    for (int n = 0; n < 4; ++n)
      acc[m][n] = (f32x4){0.f, 0.f, 0.f, 0.f};

  const int frow = lane & 15;
  const int fk   = (lane >> 4) << 3;

  auto load_tiles = [&](int kt) {
    const float* ap = aptr + kt * BK;
    const float* bp = bptr + kt * BK;
    #pragma unroll
    for (int i = 0; i < 4; ++i) sa[i] = *(const f32x4*)(ap + i * 4);
    #pragma unroll
    for (int i = 0; i < 4; ++i) sb[i] = *(const f32x4*)(bp + i * 4);
  };
  auto conv_write = [&](int buf) {
    u16* wa = &lA[buf][srow][scol];
    u16* wb = &lB[buf][srow][scol];
    bf16x8 p;
    #pragma unroll
    for (int j = 0; j < 8; ++j) p[j] = (short)f2bf(sa[j >> 2][j & 3]);
    *(bf16x8*)(wa) = p;
    #pragma unroll
    for (int j = 0; j < 8; ++j) p[j] = (short)f2bf(sa[2 + (j >> 2)][j & 3]);
    *(bf16x8*)(wa + 8) = p;
    #pragma unroll
    for (int j = 0; j < 8; ++j) p[j] = (short)f2bf(sb[j >> 2][j & 3]);
    *(bf16x8*)(wb) = p;
    #pragma unroll
    for (int j = 0; j < 8; ++j) p[j] = (short)f2bf(sb[2 + (j >> 2)][j & 3]);
    *(bf16x8*)(wb + 8) = p;
  };

  load_tiles(0);
  conv_write(0);
  __syncthreads();

  int cur = 0;
  for (int kt = 0; kt < NKT; ++kt) {
    const bool more = (kt + 1 < NKT);
    if (more) load_tiles(kt + 1);

    bf16x8 af[4], bfr[4];
    #pragma unroll
    for (int m = 0; m < 4; ++m)
      af[m] = *(const bf16x8*)&lA[cur][wr * 64 + m * 16 + frow][fk];
    #pragma unroll
    for (int n = 0; n < 4; ++n)
      bfr[n] = *(const bf16x8*)&lB[cur][wc * 64 + n * 16 + frow][fk];

    if (more) conv_write(cur ^ 1);

    #pragma unroll
    for (int m = 0; m < 4; ++m)
      #pragma unroll
      for (int n = 0; n < 4; ++n)
        acc[m][n] = __builtin_amdgcn_mfma_f32_16x16x32_bf16(af[m], bfr[n], acc[m][n], 0, 0, 0);

    __syncthreads();
    cur ^= 1;
  }

  const int crow0 = row_base + wr * 64;
  const int ccol  = col_base + wc * 64 + (lane & 15);
  const int rsub  = (lane >> 4) << 2;
  #pragma unroll
  for (int m = 0; m < 4; ++m) {
    #pragma unroll
    for (int j = 0; j < 4; ++j) {
      const int r = crow0 + m * 16 + rsub + j;
      if (r < sege) {
        #pragma unroll
        for (int n = 0; n < 4; ++n)
          C[(long long)r * NDIM + ccol + n * 16] = acc[m][n][j];
      }
    }
  }
}

extern "C" void kernel_launch(void* const* d_in, const int* in_sizes, int n_in,
                              void* d_out, int out_size, void* d_ws, size_t ws_size,
                              hipStream_t stream) {
  const float* A   = (const float*)d_in[0];
  const float* B   = (const float*)d_in[1];
  const int* segp  = (const int*)d_in[3];
  const int* widx  = (const int*)d_in[4];
  float* C = (float*)d_out;

  const size_t need = (size_t)(TA + TB) * sizeof(u16);   // 320 MB
  if (ws_size >= need) {
    u16* oA = (u16*)d_ws;
    u16* oB = oA + TA;
    cvt_bf16<<<dim3(2048), dim3(256), 0, stream>>>(A, B, oA, oB);
    (void)hipFuncSetAttribute((const void*)gg8,
                              hipFuncAttributeMaxDynamicSharedMemorySize,
                              LDS_BYTES);   // 48 KB
    gg8<<<dim3(NWG3), dim3(512), LDS_BYTES, stream>>>(oA, oB, C, segp, widx);
  } else {
    grouped_gemm_fused<<<dim3(NWG), dim3(256), 0, stream>>>(A, B, C, segp, widx);
  }
}

// Round 11
// 539.115 us; speedup vs baseline: 1.0540x; 1.0540x over previous
//
#include <hip/hip_runtime.h>
#include <hip/hip_bf16.h>

typedef float f32x4 __attribute__((ext_vector_type(4)));
typedef float f32x16 __attribute__((ext_vector_type(16)));
typedef short bf16x8 __attribute__((ext_vector_type(8)));
typedef unsigned short u16;

constexpr int T_TOK = 8192;
constexpr int KDIM  = 4096;
constexpr int NDIM  = 4096;
constexpr int NE    = 8;

constexpr long long TA = (long long)T_TOK * KDIM;
constexpr long long TB = (long long)NE * NDIM * KDIM;

__device__ __forceinline__ u16 f2bf(float f) {
  unsigned u = __builtin_bit_cast(unsigned, f);
  u += 0x7FFFu + ((u >> 16) & 1u);
  return (u16)(u >> 16);
}

// ---------------- pass 1: fp32 -> bf16 streaming convert ---------------------
__global__ __launch_bounds__(256)
void cvt_bf16(const float* __restrict__ A, const float* __restrict__ B,
              u16* __restrict__ oA, u16* __restrict__ oB) {
  const long long nv = (TA + TB) >> 3;
  const long long stride = (long long)gridDim.x * blockDim.x;
  for (long long i = (long long)blockIdx.x * blockDim.x + threadIdx.x; i < nv; i += stride) {
    const long long e = i << 3;
    const float* s;
    u16* d;
    if (e < TA) { s = A + e;        d = oA + e; }
    else        { s = B + (e - TA); d = oB + (e - TA); }
    f32x4 v0 = ((const f32x4*)s)[0];
    f32x4 v1 = ((const f32x4*)s)[1];
    bf16x8 p;
    #pragma unroll
    for (int j = 0; j < 4; ++j) p[j]     = (short)f2bf(v0[j]);
    #pragma unroll
    for (int j = 0; j < 4; ++j) p[4 + j] = (short)f2bf(v1[j]);
    *(bf16x8*)d = p;
  }
}

// ---------------- pass 2: 256x256 BK=64, 32x32x16 MFMA grouped GEMM ----------
__device__ __forceinline__ void gload16(const u16* g, const u16* l) {
  __builtin_amdgcn_global_load_lds(
      (const __attribute__((address_space(1))) void*)g,
      (__attribute__((address_space(3))) void*)l, 16, 0, 0);
}

constexpr int BM2 = 256, BN2 = 256, BK2 = 64;
constexpr int NKT2 = KDIM / BK2;          // 64 k-tiles
constexpr int NTN2 = NDIM / BN2;          // 16 n-tiles
constexpr int MT2  = T_TOK / BM2 + NE;    // 40 worst-case m-tiles
constexpr int NWG2 = MT2 * NTN2;          // 640
constexpr int ASZ  = BM2 * BK2;           // 16384 elems per buffer per operand
constexpr int HSZ  = ASZ / 2;             // 8192 elems (128-row half)

__global__ __launch_bounds__(512, 2)
void gg8(const u16* __restrict__ Abf, const u16* __restrict__ Bbf,
         float* __restrict__ C, const int* __restrict__ segp,
         const int* __restrict__ widx)
{
  extern __shared__ u16 sm[];
  u16* sA = sm;               // [2][2][8192]  (buf, half, elems); 128B rows
  u16* sB = sm + 2 * ASZ;

  int bid = (int)blockIdx.x;
  bid = (bid & 7) * (NWG2 / 8) + (bid >> 3);   // XCD-aware bijective swizzle
  const int nt = bid % NTN2;
  const int mt = bid / NTN2;

  int e = -1, segs = 0, sege = 0, mloc = 0;
  {
    int acc0 = 0, sp = segp[0];
    #pragma unroll
    for (int i = 0; i < NE; ++i) {
      int sn = segp[i + 1];
      int nti = (sn - sp + BM2 - 1) / BM2;
      if (e < 0 && mt < acc0 + nti) { e = i; mloc = mt - acc0; segs = sp; sege = sn; }
      acc0 += nti; sp = sn;
    }
  }
  if (e < 0) return;

  const int row_base = segs + mloc * BM2;
  const int col_base = nt * BN2;
  const u16* __restrict__ W = Bbf + (long long)widx[e] * ((long long)NDIM * KDIM);

  const int tid = threadIdx.x, lane = tid & 63, wid = tid >> 6;
  const int wr = wid >> 2, wc = wid & 3;

  // ---- staging: linear LDS dest, inverse-swizzled global source -------------
  // LDS half = 128 rows x 64 cols bf16 (128B rows, 8 x 16B granules/row).
  // Swizzle key k(r) = (r&7) ^ ((r>>3)&3): LDS (row, g') holds global granule
  // g' ^ k(r). Staging instr covers rows R0..R0+7 (R0 = wid*8 or 64+wid*8):
  // lane l -> row R0+(l>>3), granule l&7; (r>>3)&3 = wid&3 both instrs.
  const int sg = (((lane & 7) ^ ((lane >> 3) & 7) ^ (wid & 3)) << 3);
  const int rr = wid * 8 + (lane >> 3);               // row within 64-row block
  int oA[2][2], oB[2][2];
  #pragma unroll
  for (int h = 0; h < 2; ++h)
    #pragma unroll
    for (int i = 0; i < 2; ++i) {
      oA[h][i] = min(row_base + h * 128 + i * 64 + rr, T_TOK - 1) * KDIM + sg;
      oB[h][i] = (col_base + h * 128 + i * 64 + rr) * KDIM + sg;
    }

  // ---- fragment reads (32x32x16): row/col = lane&31, k = (lane>>5)*8 + j ---
  // Within-half row r = (wr or wc-derived)*64 + mf*32 + (lane&31):
  //   k(r) = (lane&7) ^ ((lane>>3)&3)  (mf*32, *64 terms vanish).
  // Logical granule for kstep ks = ks*2 + (lane>>5); physical = logical ^ k.
  const int klane = (lane & 7) ^ ((lane >> 3) & 3);
  int pgk[4];
  #pragma unroll
  for (int ks = 0; ks < 4; ++ks)
    pgk[ks] = ((ks * 2 + (lane >> 5)) ^ klane) * 8;
  const int rAin = (wr * 64 + (lane & 31)) * BK2;          // A: within-half elems
  const int rBin = ((wc & 1) * 64 + (lane & 31)) * BK2;    // B: within-half elems
  const int hB   = wc >> 1;                                // B half = col>=128

  f32x16 acc[2][2][2];   // [mh][mf2][nf]
  #pragma unroll
  for (int a = 0; a < 2; ++a)
    #pragma unroll
    for (int b = 0; b < 2; ++b)
      #pragma unroll
      for (int c = 0; c < 2; ++c)
        acc[a][b][c] = (f32x16)(0.f);

  auto STGA = [&](int bbuf, int h, int t) __attribute__((always_inline)) {
    gload16(Abf + oA[h][0] + t * BK2, sA + bbuf * ASZ + h * HSZ + wid * 512);
    gload16(Abf + oA[h][1] + t * BK2, sA + bbuf * ASZ + h * HSZ + 4096 + wid * 512);
  };
  auto STGB = [&](int bbuf, int h, int t) __attribute__((always_inline)) {
    gload16(W + oB[h][0] + t * BK2, sB + bbuf * ASZ + h * HSZ + wid * 512);
    gload16(W + oB[h][1] + t * BK2, sB + bbuf * ASZ + h * HSZ + 4096 + wid * 512);
  };

  // prologue: stage lo(0), hi(0), lo(1) = 12 loads/wave; vmcnt(4) -> tile0 in
  STGA(0, 0, 0); STGB(0, 0, 0); STGA(0, 1, 0); STGB(0, 1, 0);
  STGA(1, 0, 1); STGB(1, 0, 1);
  asm volatile("s_waitcnt vmcnt(4)" ::: "memory");
  __builtin_amdgcn_s_barrier();

  // r7 skeleton/ledger verbatim; frags swapped to 32x32x16.
  // p1: read B(all, own half) + A(mh0); stage {A,B}hi(t+1)->nb; 16 MFMA (mh0).
  // p2: read A(mh1); stage {A,B}lo(t+2)->bb; 16 MFMA (mh1); vmcnt(4); BAR.
  // Race audit (as r7): p1/p2 reads feed own-phase MFMAs -> lgkm-drained
  // before the phase's end barrier; every STG target's last readers are >=1
  // barrier upstream. vmcnt: start-of-tile in flight = lo(t+1) [4]; +4 +4;
  // vmcnt(4) retires lo+hi(t+1). Tail: vmcnt(0).
  bf16x8 aF[2][4], bF[2][4];
  for (int t = 0; t < NKT2; ++t) {
    const int bb = t & 1, nb = bb ^ 1;

    // p1
    #pragma unroll
    for (int nf = 0; nf < 2; ++nf)
      #pragma unroll
      for (int ks = 0; ks < 4; ++ks)
        bF[nf][ks] = *(const bf16x8*)(sB + bb * ASZ + hB * HSZ + rBin + nf * 2048 + pgk[ks]);
    #pragma unroll
    for (int mf = 0; mf < 2; ++mf)
      #pragma unroll
      for (int ks = 0; ks < 4; ++ks)
        aF[mf][ks] = *(const bf16x8*)(sA + bb * ASZ + rAin + mf * 2048 + pgk[ks]);
    if (t + 1 < NKT2) { STGA(nb, 1, t + 1); STGB(nb, 1, t + 1); }
    __builtin_amdgcn_s_setprio(1);
    #pragma unroll
    for (int ks = 0; ks < 4; ++ks)
      #pragma unroll
      for (int mf = 0; mf < 2; ++mf)
        #pragma unroll
        for (int nf = 0; nf < 2; ++nf)
          acc[0][mf][nf] = __builtin_amdgcn_mfma_f32_32x32x16_bf16(
              aF[mf][ks], bF[nf][ks], acc[0][mf][nf], 0, 0, 0);
    __builtin_amdgcn_s_setprio(0);
    __builtin_amdgcn_s_barrier();

    // p2
    #pragma unroll
    for (int mf = 0; mf < 2; ++mf)
      #pragma unroll
      for (int ks = 0; ks < 4; ++ks)
        aF[mf][ks] = *(const bf16x8*)(sA + bb * ASZ + HSZ + rAin + mf * 2048 + pgk[ks]);
    if (t + 2 < NKT2) { STGA(bb, 0, t + 2); STGB(bb, 0, t + 2); }
    __builtin_amdgcn_s_setprio(1);
    #pragma unroll
    for (int ks = 0; ks < 4; ++ks)
      #pragma unroll
      for (int mf = 0; mf < 2; ++mf)
        #pragma unroll
        for (int nf = 0; nf < 2; ++nf)
          acc[1][mf][nf] = __builtin_amdgcn_mfma_f32_32x32x16_bf16(
              aF[mf][ks], bF[nf][ks], acc[1][mf][nf], 0, 0, 0);
    __builtin_amdgcn_s_setprio(0);
    if (t + 2 < NKT2) {
      asm volatile("s_waitcnt vmcnt(4)" ::: "memory");
    } else {
      asm volatile("s_waitcnt vmcnt(0)" ::: "memory");
    }
    __builtin_amdgcn_s_barrier();
  }

  // epilogue: 32x32 C/D: col = lane&31, row = (reg&3) + 8*(reg>>2) + 4*(lane>>5)
  const int ccol = col_base + wc * 64 + (lane & 31);
  #pragma unroll
  for (int mh = 0; mh < 2; ++mh)
    #pragma unroll
    for (int mf = 0; mf < 2; ++mf) {
      const int r0 = row_base + mh * 128 + wr * 64 + mf * 32 + ((lane >> 5) << 2);
      #pragma unroll
      for (int rq = 0; rq < 4; ++rq)
        #pragma unroll
        for (int rj = 0; rj < 4; ++rj) {
          const int r = r0 + rq * 8 + rj;
          if (r < sege) {
            float* cp = C + (long long)r * NDIM + ccol;
            cp[0]  = acc[mh][mf][0][rq * 4 + rj];
            cp[32] = acc[mh][mf][1][rq * 4 + rj];
          }
        }
    }
}

// ---------------- fallback (round-1 fused convert+GEMM) ----------------------
constexpr int BM = 128, BN = 128, BK = 32;
constexpr int LDKF = BK + 8;
constexpr int NTN = NDIM / BN;
constexpr int MT_MAX = T_TOK / BM + NE;
constexpr int NKT = KDIM / BK;
constexpr int NWG = MT_MAX * NTN;

__global__ __launch_bounds__(256, 2)
void grouped_gemm_fused(const float* __restrict__ A, const float* __restrict__ B,
                        float* __restrict__ C, const int* __restrict__ segp,
                        const int* __restrict__ widx)
{
  __shared__ u16 lA[2][BM][LDKF];
  __shared__ u16 lB[2][BN][LDKF];

  const int nt = blockIdx.x % NTN;
  const int mt = blockIdx.x / NTN;

  int e = -1, segs = 0, sege = 0, mloc = 0;
  {
    int acc0 = 0, sp = segp[0];
    #pragma unroll
    for (int i = 0; i < NE; ++i) {
      int sn = segp[i + 1];
      int nti = (sn - sp + BM - 1) / BM;
      if (e < 0 && mt < acc0 + nti) { e = i; mloc = mt - acc0; segs = sp; sege = sn; }
      acc0 += nti; sp = sn;
    }
  }
  if (e < 0) return;

  const int row_base = segs + mloc * BM;
  const int col_base = nt * BN;
  const float* __restrict__ W = B + (long long)widx[e] * NDIM * KDIM;

  const int tid  = threadIdx.x;
  const int lane = tid & 63;
  const int wid  = tid >> 6;
  const int wr   = wid >> 1;
  const int wc   = wid & 1;

  const int srow = tid >> 1;
  const int scol = (tid & 1) << 4;
  const int arow = min(row_base + srow, T_TOK - 1);
  const float* __restrict__ aptr = A + (long long)arow * KDIM + scol;
  const float* __restrict__ bptr = W + (long long)(col_base + srow) * KDIM + scol;

  f32x4 sa[4], sb[4];
  f32x4 acc[4][4];
  #pragma unroll
  for (int m = 0; m < 4; ++m)
    #pragma unroll
    for (int n = 0; n < 4; ++n)
      acc[m][n] = (f32x4){0.f, 0.f, 0.f, 0.f};

  const int frow = lane & 15;
  const int fk   = (lane >> 4) << 3;

  auto load_tiles = [&](int kt) {
    const float* ap = aptr + kt * BK;
    const float* bp = bptr + kt * BK;
    #pragma unroll
    for (int i = 0; i < 4; ++i) sa[i] = *(const f32x4*)(ap + i * 4);
    #pragma unroll
    for (int i = 0; i < 4; ++i) sb[i] = *(const f32x4*)(bp + i * 4);
  };
  auto conv_write = [&](int buf) {
    u16* wa = &lA[buf][srow][scol];
    u16* wb = &lB[buf][srow][scol];
    bf16x8 p;
    #pragma unroll
    for (int j = 0; j < 8; ++j) p[j] = (short)f2bf(sa[j >> 2][j & 3]);
    *(bf16x8*)(wa) = p;
    #pragma unroll
    for (int j = 0; j < 8; ++j) p[j] = (short)f2bf(sa[2 + (j >> 2)][j & 3]);
    *(bf16x8*)(wa + 8) = p;
    #pragma unroll
    for (int j = 0; j < 8; ++j) p[j] = (short)f2bf(sb[j >> 2][j & 3]);
    *(bf16x8*)(wb) = p;
    #pragma unroll
    for (int j = 0; j < 8; ++j) p[j] = (short)f2bf(sb[2 + (j >> 2)][j & 3]);
    *(bf16x8*)(wb + 8) = p;
  };

  load_tiles(0);
  conv_write(0);
  __syncthreads();

  int cur = 0;
  for (int kt = 0; kt < NKT; ++kt) {
    const bool more = (kt + 1 < NKT);
    if (more) load_tiles(kt + 1);

    bf16x8 af[4], bfr[4];
    #pragma unroll
    for (int m = 0; m < 4; ++m)
      af[m] = *(const bf16x8*)&lA[cur][wr * 64 + m * 16 + frow][fk];
    #pragma unroll
    for (int n = 0; n < 4; ++n)
      bfr[n] = *(const bf16x8*)&lB[cur][wc * 64 + n * 16 + frow][fk];

    if (more) conv_write(cur ^ 1);

    #pragma unroll
    for (int m = 0; m < 4; ++m)
      #pragma unroll
      for (int n = 0; n < 4; ++n)
        acc[m][n] = __builtin_amdgcn_mfma_f32_16x16x32_bf16(af[m], bfr[n], acc[m][n], 0, 0, 0);

    __syncthreads();
    cur ^= 1;
  }

  const int crow0 = row_base + wr * 64;
  const int ccol  = col_base + wc * 64 + (lane & 15);
  const int rsub  = (lane >> 4) << 2;
  #pragma unroll
  for (int m = 0; m < 4; ++m) {
    #pragma unroll
    for (int j = 0; j < 4; ++j) {
      const int r = crow0 + m * 16 + rsub + j;
      if (r < sege) {
        #pragma unroll
        for (int n = 0; n < 4; ++n)
          C[(long long)r * NDIM + ccol + n * 16] = acc[m][n][j];
      }
    }
  }
}

extern "C" void kernel_launch(void* const* d_in, const int* in_sizes, int n_in,
                              void* d_out, int out_size, void* d_ws, size_t ws_size,
                              hipStream_t stream) {
  const float* A   = (const float*)d_in[0];
  const float* B   = (const float*)d_in[1];
  const int* segp  = (const int*)d_in[3];
  const int* widx  = (const int*)d_in[4];
  float* C = (float*)d_out;

  const size_t need = (size_t)(TA + TB) * sizeof(u16);   // 320 MB
  if (ws_size >= need) {
    u16* oA = (u16*)d_ws;
    u16* oB = oA + TA;
    cvt_bf16<<<dim3(2048), dim3(256), 0, stream>>>(A, B, oA, oB);
    (void)hipFuncSetAttribute((const void*)gg8,
                              hipFuncAttributeMaxDynamicSharedMemorySize,
                              2 * 2 * ASZ * (int)sizeof(u16));   // 128 KB
    gg8<<<dim3(NWG2), dim3(512), 2 * 2 * ASZ * sizeof(u16), stream>>>(oA, oB, C, segp, widx);
  } else {
    grouped_gemm_fused<<<dim3(NWG), dim3(256), 0, stream>>>(A, B, C, segp, widx);
  }
}

// Round 12
// 484.522 us; speedup vs baseline: 1.1728x; 1.1127x over previous
//
#include <hip/hip_runtime.h>
#include <hip/hip_bf16.h>

typedef float f32x4 __attribute__((ext_vector_type(4)));
typedef short bf16x8 __attribute__((ext_vector_type(8)));
typedef unsigned short u16;

constexpr int T_TOK = 8192;
constexpr int KDIM  = 4096;
constexpr int NDIM  = 4096;
constexpr int NE    = 8;

constexpr long long TA = (long long)T_TOK * KDIM;
constexpr long long TB = (long long)NE * NDIM * KDIM;

__device__ __forceinline__ u16 f2bf(float f) {
  unsigned u = __builtin_bit_cast(unsigned, f);
  u += 0x7FFFu + ((u >> 16) & 1u);
  return (u16)(u >> 16);
}

// ---------------- pass 1: fp32 -> bf16 streaming convert ---------------------
__global__ __launch_bounds__(256)
void cvt_bf16(const float* __restrict__ A, const float* __restrict__ B,
              u16* __restrict__ oA, u16* __restrict__ oB) {
  const long long nv = (TA + TB) >> 3;
  const long long stride = (long long)gridDim.x * blockDim.x;
  for (long long i = (long long)blockIdx.x * blockDim.x + threadIdx.x; i < nv; i += stride) {
    const long long e = i << 3;
    const float* s;
    u16* d;
    if (e < TA) { s = A + e;        d = oA + e; }
    else        { s = B + (e - TA); d = oB + (e - TA); }
    f32x4 v0 = ((const f32x4*)s)[0];
    f32x4 v1 = ((const f32x4*)s)[1];
    bf16x8 p;
    #pragma unroll
    for (int j = 0; j < 4; ++j) p[j]     = (short)f2bf(v0[j]);
    #pragma unroll
    for (int j = 0; j < 4; ++j) p[4 + j] = (short)f2bf(v1[j]);
    *(bf16x8*)d = p;
  }
}

// ---------------- shared helpers ---------------------------------------------
__device__ __forceinline__ void gload16(const u16* g, const u16* l) {
  __builtin_amdgcn_global_load_lds(
      (const __attribute__((address_space(1))) void*)g,
      (__attribute__((address_space(3))) void*)l, 16, 0, 0);
}

constexpr int BM2 = 256, BN2 = 256, BK2 = 64;
constexpr int NKT2 = KDIM / BK2;          // 64 k-tiles
constexpr int NTN2 = NDIM / BN2;          // 16 n-tiles
constexpr int MT2  = T_TOK / BM2 + NE;    // 40 worst-case m-tiles
constexpr int NWG_TOT = MT2 * NTN2;       // 640 worst-case tiles
constexpr int NWG_L1  = 512;              // launch-1 tiles (always >= 512 exist)
constexpr int ASZ  = BM2 * BK2;           // 16384 elems per buffer per operand
constexpr int HSZ  = ASZ / 2;             // 8192 elems (128-row half)

// expert decode shared by both kernels (256-row m-tiles)
__device__ __forceinline__ bool decode_tile(const int* segp, int mt,
                                            int& e, int& segs, int& sege, int& mloc) {
  e = -1;
  int acc0 = 0, sp = segp[0];
  #pragma unroll
  for (int i = 0; i < NE; ++i) {
    int sn = segp[i + 1];
    int nti = (sn - sp + BM2 - 1) / BM2;
    if (e < 0 && mt < acc0 + nti) { e = i; mloc = mt - acc0; segs = sp; sege = sn; }
    acc0 += nti; sp = sn;
  }
  return e >= 0;
}

// ---------------- launch 1: r7 kernel verbatim (tiles [0,512)) ---------------
__global__ __launch_bounds__(512, 2)
void gg8(const u16* __restrict__ Abf, const u16* __restrict__ Bbf,
         float* __restrict__ C, const int* __restrict__ segp,
         const int* __restrict__ widx)
{
  extern __shared__ u16 sm[];
  u16* sA = sm;               // [2][2][8192]
  u16* sB = sm + 2 * ASZ;

  int bid = (int)blockIdx.x;
  bid = (bid & 7) * (NWG_L1 / 8) + (bid >> 3);   // bijective over [0,512)
  const int nt = bid % NTN2;
  const int mt = bid / NTN2;

  int e, segs, sege, mloc;
  if (!decode_tile(segp, mt, e, segs, sege, mloc)) return;

  const int row_base = segs + mloc * BM2;
  const int col_base = nt * BN2;
  const u16* __restrict__ W = Bbf + (long long)widx[e] * ((long long)NDIM * KDIM);

  const int tid = threadIdx.x, lane = tid & 63, wid = tid >> 6;
  const int wr = wid >> 2, wc = wid & 3;

  const int sg = (((lane & 7) ^ (lane >> 3)) << 3);   // src col elems
  const int rr = wid * 8 + (lane >> 3);
  int oA[2][2], oB[2][2];
  #pragma unroll
  for (int h = 0; h < 2; ++h)
    #pragma unroll
    for (int i = 0; i < 2; ++i) {
      oA[h][i] = min(row_base + h * 128 + i * 64 + rr, T_TOK - 1) * KDIM + sg;
      oB[h][i] = (col_base + h * 128 + i * 64 + rr) * KDIM + sg;
    }

  const int g0  = (lane >> 4) ^ (lane & 7);
  const int g1  = g0 ^ 4;
  const int rA0 = (wr * 64 + (lane & 15)) * BK2 + g0 * 8;
  const int rA1 = (wr * 64 + (lane & 15)) * BK2 + g1 * 8;
  const int rB0 = (wc * 32 + (lane & 15)) * BK2 + g0 * 8;
  const int rB1 = (wc * 32 + (lane & 15)) * BK2 + g1 * 8;

  f32x4 acc[8][4];
  #pragma unroll
  for (int m = 0; m < 8; ++m)
    #pragma unroll
    for (int n = 0; n < 4; ++n)
      acc[m][n] = (f32x4){0.f, 0.f, 0.f, 0.f};

  bf16x8 aF[4][2], bF0[2][2], bF1[2][2];

  auto STGA = [&](int bbuf, int h, int t) __attribute__((always_inline)) {
    gload16(Abf + oA[h][0] + t * BK2, sA + bbuf * ASZ + h * HSZ + wid * 512);
    gload16(Abf + oA[h][1] + t * BK2, sA + bbuf * ASZ + h * HSZ + 4096 + wid * 512);
  };
  auto STGB = [&](int bbuf, int h, int t) __attribute__((always_inline)) {
    gload16(W + oB[h][0] + t * BK2, sB + bbuf * ASZ + h * HSZ + wid * 512);
    gload16(W + oB[h][1] + t * BK2, sB + bbuf * ASZ + h * HSZ + 4096 + wid * 512);
  };
  auto LDA = [&](int bbuf, int mh) __attribute__((always_inline)) {
    #pragma unroll
    for (int j = 0; j < 4; ++j) {
      const u16* p = sA + bbuf * ASZ + mh * HSZ + j * 16 * BK2;
      aF[j][0] = *(const bf16x8*)(p + rA0);
      aF[j][1] = *(const bf16x8*)(p + rA1);
    }
  };
  auto LDB = [&](int bbuf, int nh, bf16x8 (&bF)[2][2]) __attribute__((always_inline)) {
    #pragma unroll
    for (int i = 0; i < 2; ++i) {
      const u16* p = sB + bbuf * ASZ + nh * HSZ + i * 16 * BK2;
      bF[i][0] = *(const bf16x8*)(p + rB0);
      bF[i][1] = *(const bf16x8*)(p + rB1);
    }
  };
  auto MF = [&](int mh, int nh, bf16x8 (&bF)[2][2]) __attribute__((always_inline)) {
    __builtin_amdgcn_s_setprio(1);
    #pragma unroll
    for (int j = 0; j < 4; ++j)
      #pragma unroll
      for (int i = 0; i < 2; ++i) {
        acc[mh * 4 + j][nh * 2 + i] = __builtin_amdgcn_mfma_f32_16x16x32_bf16(
            aF[j][0], bF[i][0], acc[mh * 4 + j][nh * 2 + i], 0, 0, 0);
        acc[mh * 4 + j][nh * 2 + i] = __builtin_amdgcn_mfma_f32_16x16x32_bf16(
            aF[j][1], bF[i][1], acc[mh * 4 + j][nh * 2 + i], 0, 0, 0);
      }
    __builtin_amdgcn_s_setprio(0);
  };

  STGA(0, 0, 0); STGB(0, 0, 0); STGA(0, 1, 0); STGB(0, 1, 0);
  STGA(1, 0, 1); STGB(1, 0, 1);
  asm volatile("s_waitcnt vmcnt(4)" ::: "memory");
  __builtin_amdgcn_s_barrier();

  // r7 ledger (proven): in flight at tile start = lo(t+1) [4]; p1 stages
  // hi(t+1), p2 stages lo(t+2); vmcnt(4) retires tile t+1. Tail: vmcnt(0).
  for (int t = 0; t < NKT2; ++t) {
    const int bb = t & 1, nb = bb ^ 1;

    LDA(bb, 0); LDB(bb, 0, bF0); LDB(bb, 1, bF1);
    if (t + 1 < NKT2) { STGA(nb, 1, t + 1); STGB(nb, 1, t + 1); }
    MF(0, 0, bF0); MF(0, 1, bF1);
    __builtin_amdgcn_s_barrier();

    LDA(bb, 1);
    if (t + 2 < NKT2) { STGA(bb, 0, t + 2); STGB(bb, 0, t + 2); }
    MF(1, 0, bF0); MF(1, 1, bF1);
    if (t + 2 < NKT2) {
      asm volatile("s_waitcnt vmcnt(4)" ::: "memory");
    } else {
      asm volatile("s_waitcnt vmcnt(0)" ::: "memory");
    }
    __builtin_amdgcn_s_barrier();
  }

  #pragma unroll
  for (int m = 0; m < 8; ++m) {
    const int r0 = row_base + (m >> 2) * 128 + wr * 64 + (m & 3) * 16 + ((lane >> 4) << 2);
    #pragma unroll
    for (int j = 0; j < 4; ++j) {
      const int r = r0 + j;
      if (r < sege) {
        float* cp = C + (long long)r * NDIM + col_base + (lane & 15);
        #pragma unroll
        for (int n = 0; n < 4; ++n)
          cp[(n >> 1) * 128 + wc * 32 + (n & 1) * 16] = acc[m][n][j];
      }
    }
  }
}

// ---------------- launch 2: half-tile kernel (tiles [512, 640) x 2 halves) ---
// 128x256 per block (mh half of a 256^2 tile), 8 waves of 64x64, BK=64.
// LDS: sA [2][8192] + sB [2][16384] = 96 KB.
__global__ __launch_bounds__(512, 2)
void gg_half(const u16* __restrict__ Abf, const u16* __restrict__ Bbf,
             float* __restrict__ C, const int* __restrict__ segp,
             const int* __restrict__ widx)
{
  extern __shared__ u16 sm[];
  u16* sA = sm;                  // [2][8192]  (128 rows x 64)
  u16* sB = sm + 2 * HSZ;        // [2][16384] (256 rows x 64)

  int b = (int)blockIdx.x;
  const int swz = (b & 7) * 32 + (b >> 3);     // bijective over [0,256)
  const int tile = NWG_L1 + (swz >> 1);        // 512..639
  const int mh   = swz & 1;
  const int nt = tile % NTN2;
  const int mt = tile / NTN2;

  int e, segs, sege, mloc;
  if (!decode_tile(segp, mt, e, segs, sege, mloc)) return;

  const int row_base = segs + mloc * BM2 + mh * 128;   // this block's 128 rows
  const int col_base = nt * BN2;
  const u16* __restrict__ W = Bbf + (long long)widx[e] * ((long long)NDIM * KDIM);

  const int tid = threadIdx.x, lane = tid & 63, wid = tid >> 6;
  const int wr = wid >> 2, wc = wid & 3;   // wave tile 64x64: rows wr*64, cols wc*64

  // staging (r7-proven pattern): key(row) = row&7; src granule = (l&7)^(l>>3)
  const int sg = (((lane & 7) ^ (lane >> 3)) << 3);
  const int rr = wid * 8 + (lane >> 3);
  int oA[2], oB[4];
  #pragma unroll
  for (int i = 0; i < 2; ++i)
    oA[i] = min(row_base + i * 64 + rr, T_TOK - 1) * KDIM + sg;
  #pragma unroll
  for (int i = 0; i < 4; ++i)
    oB[i] = (col_base + i * 64 + rr) * KDIM + sg;

  // fragment reads: row = base + (lane&15), key = lane&7 (16-row strides ok)
  const int g0  = (lane >> 4) ^ (lane & 7);
  const int g1  = g0 ^ 4;
  const int rA0 = (wr * 64 + (lane & 15)) * BK2 + g0 * 8;
  const int rA1 = (wr * 64 + (lane & 15)) * BK2 + g1 * 8;
  const int rB0 = (wc * 64 + (lane & 15)) * BK2 + g0 * 8;
  const int rB1 = (wc * 64 + (lane & 15)) * BK2 + g1 * 8;

  f32x4 acc[4][4];
  #pragma unroll
  for (int m = 0; m < 4; ++m)
    #pragma unroll
    for (int n = 0; n < 4; ++n)
      acc[m][n] = (f32x4){0.f, 0.f, 0.f, 0.f};

  auto STAGE = [&](int bbuf, int t) __attribute__((always_inline)) {
    gload16(Abf + oA[0] + t * BK2, sA + bbuf * HSZ + wid * 512);
    gload16(Abf + oA[1] + t * BK2, sA + bbuf * HSZ + 4096 + wid * 512);
    #pragma unroll
    for (int i = 0; i < 4; ++i)
      gload16(W + oB[i] + t * BK2, sB + bbuf * ASZ + i * 4096 + wid * 512);
  };

  // prologue: t0 -> buf0, t1 -> buf1 (12 loads/wave); vmcnt(6) -> t0 landed
  STAGE(0, 0); STAGE(1, 1);
  asm volatile("s_waitcnt vmcnt(6)" ::: "memory");
  __builtin_amdgcn_s_barrier();

  // Ledger: at tile start outstanding = t+1 (6/wave); STAGE adds 6 ->
  // vmcnt(6) retires t+1 exactly. Tail (t+2>=NKT2): vmcnt(0).
  // Races: lgkm0+BAR before STAGE overwrites bb (all reads landed in regs).
  for (int t = 0; t < NKT2; ++t) {
    const int bb = t & 1;

    bf16x8 aF[4][2], bF[4][2];
    #pragma unroll
    for (int m = 0; m < 4; ++m) {
      const u16* p = sA + bb * HSZ + m * 16 * BK2;
      aF[m][0] = *(const bf16x8*)(p + rA0);
      aF[m][1] = *(const bf16x8*)(p + rA1);
    }
    #pragma unroll
    for (int n = 0; n < 4; ++n) {
      const u16* p = sB + bb * ASZ + n * 16 * BK2;
      bF[n][0] = *(const bf16x8*)(p + rB0);
      bF[n][1] = *(const bf16x8*)(p + rB1);
    }

    asm volatile("s_waitcnt lgkmcnt(0)" ::: "memory");
    __builtin_amdgcn_s_barrier();

    if (t + 2 < NKT2) STAGE(bb, t + 2);

    __builtin_amdgcn_s_setprio(1);
    #pragma unroll
    for (int m = 0; m < 4; ++m)
      #pragma unroll
      for (int n = 0; n < 4; ++n) {
        acc[m][n] = __builtin_amdgcn_mfma_f32_16x16x32_bf16(aF[m][0], bF[n][0], acc[m][n], 0, 0, 0);
        acc[m][n] = __builtin_amdgcn_mfma_f32_16x16x32_bf16(aF[m][1], bF[n][1], acc[m][n], 0, 0, 0);
      }
    __builtin_amdgcn_s_setprio(0);

    if (t + 2 < NKT2) {
      asm volatile("s_waitcnt vmcnt(6)" ::: "memory");
    } else {
      asm volatile("s_waitcnt vmcnt(0)" ::: "memory");
    }
    __builtin_amdgcn_s_barrier();
  }

  // epilogue: C/D col = lane&15, row = (lane>>4)*4 + j
  #pragma unroll
  for (int m = 0; m < 4; ++m) {
    const int r0 = row_base + wr * 64 + m * 16 + ((lane >> 4) << 2);
    #pragma unroll
    for (int j = 0; j < 4; ++j) {
      const int r = r0 + j;
      if (r < sege) {
        float* cp = C + (long long)r * NDIM + col_base + wc * 64 + (lane & 15);
        #pragma unroll
        for (int n = 0; n < 4; ++n)
          cp[n * 16] = acc[m][n][j];
      }
    }
  }
}

// ---------------- fallback (round-1 fused convert+GEMM) ----------------------
constexpr int BM = 128, BN = 128, BK = 32;
constexpr int LDKF = BK + 8;
constexpr int NTN = NDIM / BN;
constexpr int MT_MAX = T_TOK / BM + NE;
constexpr int NKT = KDIM / BK;
constexpr int NWG = MT_MAX * NTN;

__global__ __launch_bounds__(256, 2)
void grouped_gemm_fused(const float* __restrict__ A, const float* __restrict__ B,
                        float* __restrict__ C, const int* __restrict__ segp,
                        const int* __restrict__ widx)
{
  __shared__ u16 lA[2][BM][LDKF];
  __shared__ u16 lB[2][BN][LDKF];

  const int nt = blockIdx.x % NTN;
  const int mt = blockIdx.x / NTN;

  int e = -1, segs = 0, sege = 0, mloc = 0;
  {
    int acc0 = 0, sp = segp[0];
    #pragma unroll
    for (int i = 0; i < NE; ++i) {
      int sn = segp[i + 1];
      int nti = (sn - sp + BM - 1) / BM;
      if (e < 0 && mt < acc0 + nti) { e = i; mloc = mt - acc0; segs = sp; sege = sn; }
      acc0 += nti; sp = sn;
    }
  }
  if (e < 0) return;

  const int row_base = segs + mloc * BM;
  const int col_base = nt * BN;
  const float* __restrict__ W = B + (long long)widx[e] * NDIM * KDIM;

  const int tid  = threadIdx.x;
  const int lane = tid & 63;
  const int wid  = tid >> 6;
  const int wr   = wid >> 1;
  const int wc   = wid & 1;

  const int srow = tid >> 1;
  const int scol = (tid & 1) << 4;
  const int arow = min(row_base + srow, T_TOK - 1);
  const float* __restrict__ aptr = A + (long long)arow * KDIM + scol;
  const float* __restrict__ bptr = W + (long long)(col_base + srow) * KDIM + scol;

  f32x4 sa[4], sb[4];
  f32x4 acc[4][4];
  #pragma unroll
  for (int m = 0; m < 4; ++m)
    #pragma unroll
    for (int n = 0; n < 4; ++n)
      acc[m][n] = (f32x4){0.f, 0.f, 0.f, 0.f};

  const int frow = lane & 15;
  const int fk   = (lane >> 4) << 3;

  auto load_tiles = [&](int kt) {
    const float* ap = aptr + kt * BK;
    const float* bp = bptr + kt * BK;
    #pragma unroll
    for (int i = 0; i < 4; ++i) sa[i] = *(const f32x4*)(ap + i * 4);
    #pragma unroll
    for (int i = 0; i < 4; ++i) sb[i] = *(const f32x4*)(bp + i * 4);
  };
  auto conv_write = [&](int buf) {
    u16* wa = &lA[buf][srow][scol];
    u16* wb = &lB[buf][srow][scol];
    bf16x8 p;
    #pragma unroll
    for (int j = 0; j < 8; ++j) p[j] = (short)f2bf(sa[j >> 2][j & 3]);
    *(bf16x8*)(wa) = p;
    #pragma unroll
    for (int j = 0; j < 8; ++j) p[j] = (short)f2bf(sa[2 + (j >> 2)][j & 3]);
    *(bf16x8*)(wa + 8) = p;
    #pragma unroll
    for (int j = 0; j < 8; ++j) p[j] = (short)f2bf(sb[j >> 2][j & 3]);
    *(bf16x8*)(wb) = p;
    #pragma unroll
    for (int j = 0; j < 8; ++j) p[j] = (short)f2bf(sb[2 + (j >> 2)][j & 3]);
    *(bf16x8*)(wb + 8) = p;
  };

  load_tiles(0);
  conv_write(0);
  __syncthreads();

  int cur = 0;
  for (int kt = 0; kt < NKT; ++kt) {
    const bool more = (kt + 1 < NKT);
    if (more) load_tiles(kt + 1);

    bf16x8 af[4], bfr[4];
    #pragma unroll
    for (int m = 0; m < 4; ++m)
      af[m] = *(const bf16x8*)&lA[cur][wr * 64 + m * 16 + frow][fk];
    #pragma unroll
    for (int n = 0; n < 4; ++n)
      bfr[n] = *(const bf16x8*)&lB[cur][wc * 64 + n * 16 + frow][fk];

    if (more) conv_write(cur ^ 1);

    #pragma unroll
    for (int m = 0; m < 4; ++m)
      #pragma unroll
      for (int n = 0; n < 4; ++n)
        acc[m][n] = __builtin_amdgcn_mfma_f32_16x16x32_bf16(af[m], bfr[n], acc[m][n], 0, 0, 0);

    __syncthreads();
    cur ^= 1;
  }

  const int crow0 = row_base + wr * 64;
  const int ccol  = col_base + wc * 64 + (lane & 15);
  const int rsub  = (lane >> 4) << 2;
  #pragma unroll
  for (int m = 0; m < 4; ++m) {
    #pragma unroll
    for (int j = 0; j < 4; ++j) {
      const int r = crow0 + m * 16 + rsub + j;
      if (r < sege) {
        #pragma unroll
        for (int n = 0; n < 4; ++n)
          C[(long long)r * NDIM + ccol + n * 16] = acc[m][n][j];
      }
    }
  }
}

extern "C" void kernel_launch(void* const* d_in, const int* in_sizes, int n_in,
                              void* d_out, int out_size, void* d_ws, size_t ws_size,
                              hipStream_t stream) {
  const float* A   = (const float*)d_in[0];
  const float* B   = (const float*)d_in[1];
  const int* segp  = (const int*)d_in[3];
  const int* widx  = (const int*)d_in[4];
  float* C = (float*)d_out;

  const size_t need = (size_t)(TA + TB) * sizeof(u16);   // 320 MB
  if (ws_size >= need) {
    u16* oA = (u16*)d_ws;
    u16* oB = oA + TA;
    cvt_bf16<<<dim3(2048), dim3(256), 0, stream>>>(A, B, oA, oB);
    (void)hipFuncSetAttribute((const void*)gg8,
                              hipFuncAttributeMaxDynamicSharedMemorySize,
                              2 * 2 * ASZ * (int)sizeof(u16));           // 128 KB
    gg8<<<dim3(NWG_L1), dim3(512), 2 * 2 * ASZ * sizeof(u16), stream>>>(oA, oB, C, segp, widx);
    (void)hipFuncSetAttribute((const void*)gg_half,
                              hipFuncAttributeMaxDynamicSharedMemorySize,
                              2 * (HSZ + ASZ) * (int)sizeof(u16));       // 96 KB
    gg_half<<<dim3((NWG_TOT - NWG_L1) * 2), dim3(512),
              2 * (HSZ + ASZ) * sizeof(u16), stream>>>(oA, oB, C, segp, widx);
  } else {
    grouped_gemm_fused<<<dim3(NWG), dim3(256), 0, stream>>>(A, B, C, segp, widx);
  }
}

// Round 13
// 471.145 us; speedup vs baseline: 1.2061x; 1.0284x over previous
//
#include <hip/hip_runtime.h>
#include <hip/hip_bf16.h>

typedef float f32x4 __attribute__((ext_vector_type(4)));
typedef short bf16x8 __attribute__((ext_vector_type(8)));
typedef unsigned short u16;

constexpr int T_TOK = 8192;
constexpr int KDIM  = 4096;
constexpr int NDIM  = 4096;
constexpr int NE    = 8;

constexpr long long TA = (long long)T_TOK * KDIM;
constexpr long long TB = (long long)NE * NDIM * KDIM;

__device__ __forceinline__ u16 f2bf(float f) {
  unsigned u = __builtin_bit_cast(unsigned, f);
  u += 0x7FFFu + ((u >> 16) & 1u);
  return (u16)(u >> 16);
}

// ---------------- pass 1: fp32 -> bf16 streaming convert ---------------------
__global__ __launch_bounds__(256)
void cvt_bf16(const float* __restrict__ A, const float* __restrict__ B,
              u16* __restrict__ oA, u16* __restrict__ oB) {
  const long long nv = (TA + TB) >> 3;
  const long long stride = (long long)gridDim.x * blockDim.x;
  for (long long i = (long long)blockIdx.x * blockDim.x + threadIdx.x; i < nv; i += stride) {
    const long long e = i << 3;
    const float* s;
    u16* d;
    if (e < TA) { s = A + e;        d = oA + e; }
    else        { s = B + (e - TA); d = oB + (e - TA); }
    f32x4 v0 = ((const f32x4*)s)[0];
    f32x4 v1 = ((const f32x4*)s)[1];
    bf16x8 p;
    #pragma unroll
    for (int j = 0; j < 4; ++j) p[j]     = (short)f2bf(v0[j]);
    #pragma unroll
    for (int j = 0; j < 4; ++j) p[4 + j] = (short)f2bf(v1[j]);
    *(bf16x8*)d = p;
  }
}

// ---------------- shared helpers ---------------------------------------------
__device__ __forceinline__ void gload16(const u16* g, const u16* l) {
  __builtin_amdgcn_global_load_lds(
      (const __attribute__((address_space(1))) void*)g,
      (__attribute__((address_space(3))) void*)l, 16, 0, 0);
}

constexpr int BM2 = 256, BN2 = 256, BK2 = 64;
constexpr int NKT2 = KDIM / BK2;          // 64 k-tiles
constexpr int NTN2 = NDIM / BN2;          // 16 n-tiles
constexpr int MT2  = T_TOK / BM2 + NE;    // 40 worst-case m-tiles
constexpr int NWG_TOT = MT2 * NTN2;       // 640 worst-case tiles
constexpr int NWG_L1  = 512;              // full-tile blocks (always >= 512 tiles exist)
constexpr int NWG_ALL = NWG_L1 + (NWG_TOT - NWG_L1) * 2;   // 768 blocks
constexpr int ASZ  = BM2 * BK2;           // 16384 elems per buffer per operand
constexpr int HSZ  = ASZ / 2;             // 8192 elems (128-row half)

// expert decode shared by both paths (256-row m-tiles)
__device__ __forceinline__ bool decode_tile(const int* segp, int mt,
                                            int& e, int& segs, int& sege, int& mloc) {
  e = -1;
  int acc0 = 0, sp = segp[0];
  #pragma unroll
  for (int i = 0; i < NE; ++i) {
    int sn = segp[i + 1];
    int nti = (sn - sp + BM2 - 1) / BM2;
    if (e < 0 && mt < acc0 + nti) { e = i; mloc = mt - acc0; segs = sp; sege = sn; }
    acc0 += nti; sp = sn;
  }
  return e >= 0;
}

// ---------------- merged GEMM: full path (tiles [0,512)) + half path ---------
__global__ __launch_bounds__(512, 2)
void gg_merged(const u16* __restrict__ Abf, const u16* __restrict__ Bbf,
               float* __restrict__ C, const int* __restrict__ segp,
               const int* __restrict__ widx)
{
  extern __shared__ u16 sm[];

  const int tid = threadIdx.x, lane = tid & 63, wid = tid >> 6;
  const int bid0 = (int)blockIdx.x;

  if (bid0 < NWG_L1) {
    // ================= FULL PATH (r7 kernel verbatim, tiles [0,512)) =========
    u16* sA = sm;               // [2][2][8192]
    u16* sB = sm + 2 * ASZ;

    int bid = (bid0 & 7) * (NWG_L1 / 8) + (bid0 >> 3);   // bijective over [0,512)
    const int nt = bid % NTN2;
    const int mt = bid / NTN2;

    int e, segs, sege, mloc;
    if (!decode_tile(segp, mt, e, segs, sege, mloc)) return;

    const int row_base = segs + mloc * BM2;
    const int col_base = nt * BN2;
    const u16* __restrict__ W = Bbf + (long long)widx[e] * ((long long)NDIM * KDIM);

    const int wr = wid >> 2, wc = wid & 3;

    const int sg = (((lane & 7) ^ (lane >> 3)) << 3);
    const int rr = wid * 8 + (lane >> 3);
    int oA[2][2], oB[2][2];
    #pragma unroll
    for (int h = 0; h < 2; ++h)
      #pragma unroll
      for (int i = 0; i < 2; ++i) {
        oA[h][i] = min(row_base + h * 128 + i * 64 + rr, T_TOK - 1) * KDIM + sg;
        oB[h][i] = (col_base + h * 128 + i * 64 + rr) * KDIM + sg;
      }

    const int g0  = (lane >> 4) ^ (lane & 7);
    const int g1  = g0 ^ 4;
    const int rA0 = (wr * 64 + (lane & 15)) * BK2 + g0 * 8;
    const int rA1 = (wr * 64 + (lane & 15)) * BK2 + g1 * 8;
    const int rB0 = (wc * 32 + (lane & 15)) * BK2 + g0 * 8;
    const int rB1 = (wc * 32 + (lane & 15)) * BK2 + g1 * 8;

    f32x4 acc[8][4];
    #pragma unroll
    for (int m = 0; m < 8; ++m)
      #pragma unroll
      for (int n = 0; n < 4; ++n)
        acc[m][n] = (f32x4){0.f, 0.f, 0.f, 0.f};

    bf16x8 aF[4][2], bF0[2][2], bF1[2][2];

    auto STGA = [&](int bbuf, int h, int t) __attribute__((always_inline)) {
      gload16(Abf + oA[h][0] + t * BK2, sA + bbuf * ASZ + h * HSZ + wid * 512);
      gload16(Abf + oA[h][1] + t * BK2, sA + bbuf * ASZ + h * HSZ + 4096 + wid * 512);
    };
    auto STGB = [&](int bbuf, int h, int t) __attribute__((always_inline)) {
      gload16(W + oB[h][0] + t * BK2, sB + bbuf * ASZ + h * HSZ + wid * 512);
      gload16(W + oB[h][1] + t * BK2, sB + bbuf * ASZ + h * HSZ + 4096 + wid * 512);
    };
    auto LDA = [&](int bbuf, int mh) __attribute__((always_inline)) {
      #pragma unroll
      for (int j = 0; j < 4; ++j) {
        const u16* p = sA + bbuf * ASZ + mh * HSZ + j * 16 * BK2;
        aF[j][0] = *(const bf16x8*)(p + rA0);
        aF[j][1] = *(const bf16x8*)(p + rA1);
      }
    };
    auto LDB = [&](int bbuf, int nh, bf16x8 (&bF)[2][2]) __attribute__((always_inline)) {
      #pragma unroll
      for (int i = 0; i < 2; ++i) {
        const u16* p = sB + bbuf * ASZ + nh * HSZ + i * 16 * BK2;
        bF[i][0] = *(const bf16x8*)(p + rB0);
        bF[i][1] = *(const bf16x8*)(p + rB1);
      }
    };
    auto MF = [&](int mh, int nh, bf16x8 (&bF)[2][2]) __attribute__((always_inline)) {
      __builtin_amdgcn_s_setprio(1);
      #pragma unroll
      for (int j = 0; j < 4; ++j)
        #pragma unroll
        for (int i = 0; i < 2; ++i) {
          acc[mh * 4 + j][nh * 2 + i] = __builtin_amdgcn_mfma_f32_16x16x32_bf16(
              aF[j][0], bF[i][0], acc[mh * 4 + j][nh * 2 + i], 0, 0, 0);
          acc[mh * 4 + j][nh * 2 + i] = __builtin_amdgcn_mfma_f32_16x16x32_bf16(
              aF[j][1], bF[i][1], acc[mh * 4 + j][nh * 2 + i], 0, 0, 0);
        }
      __builtin_amdgcn_s_setprio(0);
    };

    STGA(0, 0, 0); STGB(0, 0, 0); STGA(0, 1, 0); STGB(0, 1, 0);
    STGA(1, 0, 1); STGB(1, 0, 1);
    asm volatile("s_waitcnt vmcnt(4)" ::: "memory");
    __builtin_amdgcn_s_barrier();

    // r7 ledger (proven): in flight at tile start = lo(t+1) [4]; p1 stages
    // hi(t+1), p2 stages lo(t+2); vmcnt(4) retires tile t+1. Tail: vmcnt(0).
    for (int t = 0; t < NKT2; ++t) {
      const int bb = t & 1, nb = bb ^ 1;

      LDA(bb, 0); LDB(bb, 0, bF0); LDB(bb, 1, bF1);
      if (t + 1 < NKT2) { STGA(nb, 1, t + 1); STGB(nb, 1, t + 1); }
      MF(0, 0, bF0); MF(0, 1, bF1);
      __builtin_amdgcn_s_barrier();

      LDA(bb, 1);
      if (t + 2 < NKT2) { STGA(bb, 0, t + 2); STGB(bb, 0, t + 2); }
      MF(1, 0, bF0); MF(1, 1, bF1);
      if (t + 2 < NKT2) {
        asm volatile("s_waitcnt vmcnt(4)" ::: "memory");
      } else {
        asm volatile("s_waitcnt vmcnt(0)" ::: "memory");
      }
      __builtin_amdgcn_s_barrier();
    }

    #pragma unroll
    for (int m = 0; m < 8; ++m) {
      const int r0 = row_base + (m >> 2) * 128 + wr * 64 + (m & 3) * 16 + ((lane >> 4) << 2);
      #pragma unroll
      for (int j = 0; j < 4; ++j) {
        const int r = r0 + j;
        if (r < sege) {
          float* cp = C + (long long)r * NDIM + col_base + (lane & 15);
          #pragma unroll
          for (int n = 0; n < 4; ++n)
            cp[(n >> 1) * 128 + wc * 32 + (n & 1) * 16] = acc[m][n][j];
        }
      }
    }
  } else {
    // ================= HALF PATH (tiles [512,640) x 2 halves) ================
    u16* sA = sm;                  // [2][8192]  (128 rows x 64)
    u16* sB = sm + 2 * HSZ;        // [2][16384] (256 rows x 64)

    const int b = bid0 - NWG_L1;                 // 0..255
    const int swz = (b & 7) * 32 + (b >> 3);     // bijective over [0,256)
    const int tile = NWG_L1 + (swz >> 1);        // 512..639
    const int mh   = swz & 1;
    const int nt = tile % NTN2;
    const int mt = tile / NTN2;

    int e, segs, sege, mloc;
    if (!decode_tile(segp, mt, e, segs, sege, mloc)) return;

    const int row_base = segs + mloc * BM2 + mh * 128;
    const int col_base = nt * BN2;
    const u16* __restrict__ W = Bbf + (long long)widx[e] * ((long long)NDIM * KDIM);

    const int wr = wid >> 2, wc = wid & 3;

    const int sg = (((lane & 7) ^ (lane >> 3)) << 3);
    const int rr = wid * 8 + (lane >> 3);
    int oA[2], oB[4];
    #pragma unroll
    for (int i = 0; i < 2; ++i)
      oA[i] = min(row_base + i * 64 + rr, T_TOK - 1) * KDIM + sg;
    #pragma unroll
    for (int i = 0; i < 4; ++i)
      oB[i] = (col_base + i * 64 + rr) * KDIM + sg;

    const int g0  = (lane >> 4) ^ (lane & 7);
    const int g1  = g0 ^ 4;
    const int rA0 = (wr * 64 + (lane & 15)) * BK2 + g0 * 8;
    const int rA1 = (wr * 64 + (lane & 15)) * BK2 + g1 * 8;
    const int rB0 = (wc * 64 + (lane & 15)) * BK2 + g0 * 8;
    const int rB1 = (wc * 64 + (lane & 15)) * BK2 + g1 * 8;

    f32x4 acc[4][4];
    #pragma unroll
    for (int m = 0; m < 4; ++m)
      #pragma unroll
      for (int n = 0; n < 4; ++n)
        acc[m][n] = (f32x4){0.f, 0.f, 0.f, 0.f};

    auto STAGE = [&](int bbuf, int t) __attribute__((always_inline)) {
      gload16(Abf + oA[0] + t * BK2, sA + bbuf * HSZ + wid * 512);
      gload16(Abf + oA[1] + t * BK2, sA + bbuf * HSZ + 4096 + wid * 512);
      #pragma unroll
      for (int i = 0; i < 4; ++i)
        gload16(W + oB[i] + t * BK2, sB + bbuf * ASZ + i * 4096 + wid * 512);
    };

    STAGE(0, 0); STAGE(1, 1);
    asm volatile("s_waitcnt vmcnt(6)" ::: "memory");
    __builtin_amdgcn_s_barrier();

    // Ledger: at tile start outstanding = t+1 (6/wave); STAGE adds 6 ->
    // vmcnt(6) retires t+1 exactly. Tail (t+2>=NKT2): vmcnt(0).
    for (int t = 0; t < NKT2; ++t) {
      const int bb = t & 1;

      bf16x8 aF[4][2], bF[4][2];
      #pragma unroll
      for (int m = 0; m < 4; ++m) {
        const u16* p = sA + bb * HSZ + m * 16 * BK2;
        aF[m][0] = *(const bf16x8*)(p + rA0);
        aF[m][1] = *(const bf16x8*)(p + rA1);
      }
      #pragma unroll
      for (int n = 0; n < 4; ++n) {
        const u16* p = sB + bb * ASZ + n * 16 * BK2;
        bF[n][0] = *(const bf16x8*)(p + rB0);
        bF[n][1] = *(const bf16x8*)(p + rB1);
      }

      asm volatile("s_waitcnt lgkmcnt(0)" ::: "memory");
      __builtin_amdgcn_s_barrier();

      if (t + 2 < NKT2) STAGE(bb, t + 2);

      __builtin_amdgcn_s_setprio(1);
      #pragma unroll
      for (int m = 0; m < 4; ++m)
        #pragma unroll
        for (int n = 0; n < 4; ++n) {
          acc[m][n] = __builtin_amdgcn_mfma_f32_16x16x32_bf16(aF[m][0], bF[n][0], acc[m][n], 0, 0, 0);
          acc[m][n] = __builtin_amdgcn_mfma_f32_16x16x32_bf16(aF[m][1], bF[n][1], acc[m][n], 0, 0, 0);
        }
      __builtin_amdgcn_s_setprio(0);

      if (t + 2 < NKT2) {
        asm volatile("s_waitcnt vmcnt(6)" ::: "memory");
      } else {
        asm volatile("s_waitcnt vmcnt(0)" ::: "memory");
      }
      __builtin_amdgcn_s_barrier();
    }

    #pragma unroll
    for (int m = 0; m < 4; ++m) {
      const int r0 = row_base + wr * 64 + m * 16 + ((lane >> 4) << 2);
      #pragma unroll
      for (int j = 0; j < 4; ++j) {
        const int r = r0 + j;
        if (r < sege) {
          float* cp = C + (long long)r * NDIM + col_base + wc * 64 + (lane & 15);
          #pragma unroll
          for (int n = 0; n < 4; ++n)
            cp[n * 16] = acc[m][n][j];
        }
      }
    }
  }
}

// ---------------- fallback (round-1 fused convert+GEMM) ----------------------
constexpr int BM = 128, BN = 128, BK = 32;
constexpr int LDKF = BK + 8;
constexpr int NTN = NDIM / BN;
constexpr int MT_MAX = T_TOK / BM + NE;
constexpr int NKT = KDIM / BK;
constexpr int NWG = MT_MAX * NTN;

__global__ __launch_bounds__(256, 2)
void grouped_gemm_fused(const float* __restrict__ A, const float* __restrict__ B,
                        float* __restrict__ C, const int* __restrict__ segp,
                        const int* __restrict__ widx)
{
  __shared__ u16 lA[2][BM][LDKF];
  __shared__ u16 lB[2][BN][LDKF];

  const int nt = blockIdx.x % NTN;
  const int mt = blockIdx.x / NTN;

  int e = -1, segs = 0, sege = 0, mloc = 0;
  {
    int acc0 = 0, sp = segp[0];
    #pragma unroll
    for (int i = 0; i < NE; ++i) {
      int sn = segp[i + 1];
      int nti = (sn - sp + BM - 1) / BM;
      if (e < 0 && mt < acc0 + nti) { e = i; mloc = mt - acc0; segs = sp; sege = sn; }
      acc0 += nti; sp = sn;
    }
  }
  if (e < 0) return;

  const int row_base = segs + mloc * BM;
  const int col_base = nt * BN;
  const float* __restrict__ W = B + (long long)widx[e] * NDIM * KDIM;

  const int tid  = threadIdx.x;
  const int lane = tid & 63;
  const int wid  = tid >> 6;
  const int wr   = wid >> 1;
  const int wc   = wid & 1;

  const int srow = tid >> 1;
  const int scol = (tid & 1) << 4;
  const int arow = min(row_base + srow, T_TOK - 1);
  const float* __restrict__ aptr = A + (long long)arow * KDIM + scol;
  const float* __restrict__ bptr = W + (long long)(col_base + srow) * KDIM + scol;

  f32x4 sa[4], sb[4];
  f32x4 acc[4][4];
  #pragma unroll
  for (int m = 0; m < 4; ++m)
    #pragma unroll
    for (int n = 0; n < 4; ++n)
      acc[m][n] = (f32x4){0.f, 0.f, 0.f, 0.f};

  const int frow = lane & 15;
  const int fk   = (lane >> 4) << 3;

  auto load_tiles = [&](int kt) {
    const float* ap = aptr + kt * BK;
    const float* bp = bptr + kt * BK;
    #pragma unroll
    for (int i = 0; i < 4; ++i) sa[i] = *(const f32x4*)(ap + i * 4);
    #pragma unroll
    for (int i = 0; i < 4; ++i) sb[i] = *(const f32x4*)(bp + i * 4);
  };
  auto conv_write = [&](int buf) {
    u16* wa = &lA[buf][srow][scol];
    u16* wb = &lB[buf][srow][scol];
    bf16x8 p;
    #pragma unroll
    for (int j = 0; j < 8; ++j) p[j] = (short)f2bf(sa[j >> 2][j & 3]);
    *(bf16x8*)(wa) = p;
    #pragma unroll
    for (int j = 0; j < 8; ++j) p[j] = (short)f2bf(sa[2 + (j >> 2)][j & 3]);
    *(bf16x8*)(wa + 8) = p;
    #pragma unroll
    for (int j = 0; j < 8; ++j) p[j] = (short)f2bf(sb[j >> 2][j & 3]);
    *(bf16x8*)(wb) = p;
    #pragma unroll
    for (int j = 0; j < 8; ++j) p[j] = (short)f2bf(sb[2 + (j >> 2)][j & 3]);
    *(bf16x8*)(wb + 8) = p;
  };

  load_tiles(0);
  conv_write(0);
  __syncthreads();

  int cur = 0;
  for (int kt = 0; kt < NKT; ++kt) {
    const bool more = (kt + 1 < NKT);
    if (more) load_tiles(kt + 1);

    bf16x8 af[4], bfr[4];
    #pragma unroll
    for (int m = 0; m < 4; ++m)
      af[m] = *(const bf16x8*)&lA[cur][wr * 64 + m * 16 + frow][fk];
    #pragma unroll
    for (int n = 0; n < 4; ++n)
      bfr[n] = *(const bf16x8*)&lB[cur][wc * 64 + n * 16 + frow][fk];

    if (more) conv_write(cur ^ 1);

    #pragma unroll
    for (int m = 0; m < 4; ++m)
      #pragma unroll
      for (int n = 0; n < 4; ++n)
        acc[m][n] = __builtin_amdgcn_mfma_f32_16x16x32_bf16(af[m], bfr[n], acc[m][n], 0, 0, 0);

    __syncthreads();
    cur ^= 1;
  }

  const int crow0 = row_base + wr * 64;
  const int ccol  = col_base + wc * 64 + (lane & 15);
  const int rsub  = (lane >> 4) << 2;
  #pragma unroll
  for (int m = 0; m < 4; ++m) {
    #pragma unroll
    for (int j = 0; j < 4; ++j) {
      const int r = crow0 + m * 16 + rsub + j;
      if (r < sege) {
        #pragma unroll
        for (int n = 0; n < 4; ++n)
          C[(long long)r * NDIM + ccol + n * 16] = acc[m][n][j];
      }
    }
  }
}

extern "C" void kernel_launch(void* const* d_in, const int* in_sizes, int n_in,
                              void* d_out, int out_size, void* d_ws, size_t ws_size,
                              hipStream_t stream) {
  const float* A   = (const float*)d_in[0];
  const float* B   = (const float*)d_in[1];
  const int* segp  = (const int*)d_in[3];
  const int* widx  = (const int*)d_in[4];
  float* C = (float*)d_out;

  const size_t need = (size_t)(TA + TB) * sizeof(u16);   // 320 MB
  if (ws_size >= need) {
    u16* oA = (u16*)d_ws;
    u16* oB = oA + TA;
    cvt_bf16<<<dim3(2048), dim3(256), 0, stream>>>(A, B, oA, oB);
    (void)hipFuncSetAttribute((const void*)gg_merged,
                              hipFuncAttributeMaxDynamicSharedMemorySize,
                              2 * 2 * ASZ * (int)sizeof(u16));           // 128 KB
    gg_merged<<<dim3(NWG_ALL), dim3(512), 2 * 2 * ASZ * sizeof(u16), stream>>>(
        oA, oB, C, segp, widx);
  } else {
    grouped_gemm_fused<<<dim3(NWG), dim3(256), 0, stream>>>(A, B, C, segp, widx);
  }
}